// Round 1
// baseline (4717.260 us; speedup 1.0000x reference)
//
#include <hip/hip_runtime.h>
#include <hip/hip_bf16.h>

// Problem constants
#define NUM_CLASSES 20
#define N_ROIS 256
#define POOL 7
#define HH 12
#define WW 12
#define CC 512
#define AA 9
#define NOBJ (HH*WW*AA)        // 1296
#define D_IN (POOL*POOL*CC)    // 25088
#define D6 9216
#define D7 4096
#define D75 2048

// ---------------------------------------------------------------------------
// Kernel 1: top-k select (stable descending) + box int'ization
// ---------------------------------------------------------------------------
__global__ __launch_bounds__(256) void topk_kernel(
    const float* __restrict__ obj, const float* __restrict__ rois_norm,
    int* __restrict__ rois_int, float* __restrict__ out_rois)
{
    __shared__ float so[NOBJ];
    for (int i = threadIdx.x; i < NOBJ; i += 256) so[i] = obj[i];
    __syncthreads();
    int i = blockIdx.x * 256 + threadIdx.x;
    if (i >= NOBJ) return;
    float v = so[i];
    int rank = 0;
    for (int j = 0; j < NOBJ; j++) {
        float u = so[j];
        rank += (u > v) || (u == v && j < i);
    }
    if (rank < N_ROIS) {
        float s0 = rois_norm[i*4+0], s1 = rois_norm[i*4+1];
        float s2 = rois_norm[i*4+2], s3 = rois_norm[i*4+3];
        float x1f = __fmul_rn(s0, 12.0f);
        float x2f = __fmul_rn(s1, 12.0f);
        float y1f = __fmul_rn(s2, 12.0f);
        float y2f = __fmul_rn(s3, 12.0f);
        int x1i = min(max((int)x1f, 0), HH - 1);
        int y1i = min(max((int)y1f, 0), WW - 1);
        int x2i = max(min(max((int)x2f, 0), HH), x1i + 1);
        int y2i = max(min(max((int)y2f, 0), WW), y1i + 1);
        rois_int[rank*4+0] = x1i; rois_int[rank*4+1] = x2i;
        rois_int[rank*4+2] = y1i; rois_int[rank*4+3] = y2i;
        out_rois[rank*4+0] = (float)x1i; out_rois[rank*4+1] = (float)x2i;
        out_rois[rank*4+2] = (float)y1i; out_rois[rank*4+3] = (float)y2i;
    }
}

// ---------------------------------------------------------------------------
// Kernel 2: crop + bilinear resize -> x (N_ROIS, 7*7*512)
// ---------------------------------------------------------------------------
__global__ __launch_bounds__(256) void crop_kernel(
    const float* __restrict__ feats, const int* __restrict__ rois,
    float* __restrict__ xout)
{
    int r = blockIdx.x;
    __shared__ int y0s[POOL], y1s[POOL], x0s[POOL], x1s[POOL];
    __shared__ float wys[POOL], wxs[POOL];
    if (threadIdx.x == 0) {
        int bx1 = rois[r*4+0], bx2 = rois[r*4+1];
        int by1 = rois[r*4+2], by2 = rois[r*4+3];
        float hf = (float)(by2 - by1), wf = (float)(bx2 - bx1);
        float y1f = (float)by1, y2m1 = (float)(by2 - 1);
        float x1f = (float)bx1, x2m1 = (float)(bx2 - 1);
        for (int i = 0; i < POOL; i++) {
            float g = __fdiv_rn(__fadd_rn((float)i, 0.5f), 7.0f);
            // ys = clip((y1 + g*hf) - 0.5, y1, y2-1)  (no fma contraction!)
            float ys = __fadd_rn(__fadd_rn(y1f, __fmul_rn(g, hf)), -0.5f);
            ys = fminf(fmaxf(ys, y1f), y2m1);
            float xs = __fadd_rn(__fadd_rn(x1f, __fmul_rn(g, wf)), -0.5f);
            xs = fminf(fmaxf(xs, x1f), x2m1);
            int y0 = (int)floorf(ys);
            int x0 = (int)floorf(xs);
            y0s[i] = y0; x0s[i] = x0;
            y1s[i] = min(y0 + 1, WW - 1);
            x1s[i] = min(x0 + 1, HH - 1);
            wys[i] = __fadd_rn(ys, -(float)y0);
            wxs[i] = __fadd_rn(xs, -(float)x0);
        }
    }
    __syncthreads();
    for (int idx = threadIdx.x; idx < D_IN; idx += 256) {
        int c = idx & (CC - 1);
        int ij = idx >> 9;
        int j = ij % POOL, i = ij / POOL;
        float wy = wys[i], wx = wxs[j];
        int y0 = y0s[i], y1n = y1s[i], x0 = x0s[j], x1n = x1s[j];
        float f00 = feats[(y0 * WW + x0 ) * CC + c];
        float f01 = feats[(y0 * WW + x1n) * CC + c];
        float f10 = feats[(y1n* WW + x0 ) * CC + c];
        float f11 = feats[(y1n* WW + x1n) * CC + c];
        float v = f00 * (1.f - wy) * (1.f - wx)
                + f01 * (1.f - wy) * wx
                + f10 * wy * (1.f - wx)
                + f11 * wy * wx;
        xout[(size_t)r * D_IN + idx] = v;
    }
}

// ---------------------------------------------------------------------------
// Kernel 3: tiled f32 GEMM  C = relu(A @ B + bias)
// A: (M,K) row-major, B: (K,N) row-major, C: (M,N)
// ---------------------------------------------------------------------------
#define TM 64
#define TN 64
#define TK 16
#define PAD 68

__global__ __launch_bounds__(256) void gemm_bias_relu(
    const float* __restrict__ A, const float* __restrict__ B,
    const float* __restrict__ bias, float* __restrict__ C,
    int M, int N, int K, int do_relu)
{
    __shared__ float As[TK][PAD];
    __shared__ float Bs[TK][PAD];
    int tid = threadIdx.x;
    int tx = tid % 16;
    int ty = tid / 16;
    int m0 = blockIdx.y * TM;
    int n0 = blockIdx.x * TN;
    int ak = tid % 16, am = tid / 16;
    int bn = tid % 64, bk = tid / 64;
    float acc[4][4] = {};
    for (int k0 = 0; k0 < K; k0 += TK) {
#pragma unroll
        for (int i = 0; i < 4; i++)
            As[ak][am + 16*i] = A[(size_t)(m0 + am + 16*i) * K + k0 + ak];
#pragma unroll
        for (int i = 0; i < 4; i++)
            Bs[bk + 4*i][bn] = B[(size_t)(k0 + bk + 4*i) * N + n0 + bn];
        __syncthreads();
#pragma unroll
        for (int k = 0; k < TK; k++) {
            float a[4], b[4];
#pragma unroll
            for (int i = 0; i < 4; i++) a[i] = As[k][ty*4 + i];
#pragma unroll
            for (int j = 0; j < 4; j++) b[j] = Bs[k][tx*4 + j];
#pragma unroll
            for (int i = 0; i < 4; i++)
#pragma unroll
                for (int j = 0; j < 4; j++)
                    acc[i][j] += a[i] * b[j];
        }
        __syncthreads();
    }
#pragma unroll
    for (int i = 0; i < 4; i++) {
        int m = m0 + ty*4 + i;
#pragma unroll
        for (int j = 0; j < 4; j++) {
            int n = n0 + tx*4 + j;
            float v = acc[i][j] + bias[n];
            if (do_relu) v = fmaxf(v, 0.f);
            C[(size_t)m * N + n] = v;
        }
    }
}

// ---------------------------------------------------------------------------
// Kernel 4: classification/detection logits (per-ROI block)
// ---------------------------------------------------------------------------
__global__ __launch_bounds__(256) void logits_kernel(
    const float* __restrict__ fc,
    const float* __restrict__ Wc, const float* __restrict__ bc,
    const float* __restrict__ Wd, const float* __restrict__ bd,
    float* __restrict__ cls_logits, float* __restrict__ det_logits)
{
    int r = blockIdx.x;
    __shared__ float row[D75];
    for (int d = threadIdx.x; d < D75; d += 256) row[d] = fc[(size_t)r * D75 + d];
    __syncthreads();
    int t = threadIdx.x;
    if (t < NUM_CLASSES) {
        float s = 0.f;
        for (int d = 0; d < D75; d++) s += row[d] * Wc[d * NUM_CLASSES + t];
        cls_logits[r * NUM_CLASSES + t] = s + bc[t];
    } else if (t >= 64 && t < 64 + NUM_CLASSES) {
        int k = t - 64;
        float s = 0.f;
        for (int d = 0; d < D75; d++) s += row[d] * Wd[d * NUM_CLASSES + k];
        det_logits[r * NUM_CLASSES + k] = s + bd[k];
    }
}

// ---------------------------------------------------------------------------
// Kernel 5: softmaxes, scores, column sums (output 0), argmin per class
// One block of 256 threads (thread == ROI).
// ---------------------------------------------------------------------------
__global__ __launch_bounds__(256) void scores_kernel(
    const float* __restrict__ cls_logits, const float* __restrict__ det_logits,
    float* __restrict__ scores_ws, float* __restrict__ out_scores,
    float* __restrict__ out_sums, int* __restrict__ top_idx)
{
    __shared__ float cl[N_ROIS][NUM_CLASSES];
    __shared__ float dv[N_ROIS][NUM_CLASSES];
    __shared__ float cmax[NUM_CLASSES], csum[NUM_CLASSES];
    int r = threadIdx.x;
    // det softmax over classes (axis=1)
    float dl[NUM_CLASSES];
    float m = -1e30f;
    for (int k = 0; k < NUM_CLASSES; k++) {
        dl[k] = det_logits[r * NUM_CLASSES + k];
        m = fmaxf(m, dl[k]);
    }
    float s = 0.f;
    for (int k = 0; k < NUM_CLASSES; k++) { dl[k] = expf(dl[k] - m); s += dl[k]; }
    for (int k = 0; k < NUM_CLASSES; k++) dv[r][k] = dl[k] / s;
    for (int k = 0; k < NUM_CLASSES; k++) cl[r][k] = cls_logits[r * NUM_CLASSES + k];
    __syncthreads();
    // cls softmax over ROIs (axis=0): column stats
    if (r < NUM_CLASSES) {
        float mm = -1e30f;
        for (int i = 0; i < N_ROIS; i++) mm = fmaxf(mm, cl[i][r]);
        float ss = 0.f;
        for (int i = 0; i < N_ROIS; i++) ss += expf(cl[i][r] - mm);
        cmax[r] = mm; csum[r] = ss;
    }
    __syncthreads();
    float sc[NUM_CLASSES];
    for (int k = 0; k < NUM_CLASSES; k++) {
        sc[k] = (expf(cl[r][k] - cmax[k]) / csum[k]) * dv[r][k];
        scores_ws[r * NUM_CLASSES + k] = sc[k];
        out_scores[r * NUM_CLASSES + k] = sc[k];
    }
    __syncthreads();
    for (int k = 0; k < NUM_CLASSES; k++) cl[r][k] = sc[k];  // reuse LDS
    __syncthreads();
    if (r < NUM_CLASSES) {
        float sum = 0.f, mn = 1e30f;
        int mi = 0;
        for (int i = 0; i < N_ROIS; i++) {
            float v = cl[i][r];
            sum += v;
            if (v < mn) { mn = v; mi = i; }
        }
        out_sums[r] = fminf(fmaxf(sum, 0.f), 1.f);
        top_idx[r] = mi;
    }
}

// ---------------------------------------------------------------------------
// Kernel 6: per-row squared norms of fc
// ---------------------------------------------------------------------------
__global__ __launch_bounds__(256) void norms_kernel(
    const float* __restrict__ fc, float* __restrict__ norms)
{
    int r = blockIdx.x;
    float s = 0.f;
    for (int d = threadIdx.x; d < D75; d += 256) {
        float v = fc[(size_t)r * D75 + d];
        s += v * v;
    }
    __shared__ float red[256];
    red[threadIdx.x] = s;
    __syncthreads();
    for (int off = 128; off > 0; off >>= 1) {
        if (threadIdx.x < off) red[threadIdx.x] += red[threadIdx.x + off];
        __syncthreads();
    }
    if (threadIdx.x == 0) norms[r] = red[0];
}

// ---------------------------------------------------------------------------
// Kernel 7: dots[r][k] = fc[r] . fc[top_idx[k]]
// ---------------------------------------------------------------------------
__global__ __launch_bounds__(64) void dots_kernel(
    const float* __restrict__ fc, const int* __restrict__ top_idx,
    float* __restrict__ dots)
{
    int r = blockIdx.x, k = blockIdx.y;
    int t = top_idx[k];
    const float* a = fc + (size_t)r * D75;
    const float* b = fc + (size_t)t * D75;
    float s = 0.f;
    for (int d = threadIdx.x; d < D75; d += 64) s += a[d] * b[d];
    for (int off = 32; off > 0; off >>= 1) s += __shfl_down(s, off);
    if (threadIdx.x == 0) dots[r * NUM_CLASSES + k] = s;
}

// ---------------------------------------------------------------------------
// Kernel 8: spatial regularization scalar
// ---------------------------------------------------------------------------
__global__ __launch_bounds__(64) void reg_kernel(
    const int* __restrict__ labels, const int* __restrict__ rois,
    const int* __restrict__ top_idx, const float* __restrict__ norms,
    const float* __restrict__ dots, const float* __restrict__ scores,
    float* __restrict__ out_reg)
{
    __shared__ float vals[NUM_CLASSES];
    int k = threadIdx.x;
    if (k < NUM_CLASSES) {
        float v = 0.f;
        if (labels[k] > 0) {
            int t = top_idx[k];
            float T = norms[t];
            float rx1 = (float)rois[t*4+0], rx2 = (float)rois[t*4+1];
            float ry1 = (float)rois[t*4+2], ry2 = (float)rois[t*4+3];
            float aref = fmaxf(rx2 - rx1 + 1.f, 0.f) * fmaxf(ry2 - ry1 + 1.f, 0.f);
            float acc = 0.f;
            for (int r = 0; r < N_ROIS; r++) {
                if (r == t) continue;
                float bx1 = (float)rois[r*4+0], bx2 = (float)rois[r*4+1];
                float by1 = (float)rois[r*4+2], by2 = (float)rois[r*4+3];
                float ix1 = fmaxf(bx1, rx1), iy1 = fmaxf(by1, ry1);
                float ix2 = fminf(bx2, rx2), iy2 = fminf(by2, ry2);
                float inter = fmaxf(ix2 - ix1 + 1.f, 0.f) * fmaxf(iy2 - iy1 + 1.f, 0.f);
                float a1 = fmaxf(bx2 - bx1 + 1.f, 0.f) * fmaxf(by2 - by1 + 1.f, 0.f);
                float iou = inter / (a1 + aref - inter);
                float s = scores[r * NUM_CLASSES + k];
                float term = (iou > 0.5f)
                           ? (norms[r] - 2.f * dots[r * NUM_CLASSES + k] + T)
                           : T;
                acc += s * s * term;
            }
            v = 0.5f * acc;
        }
        vals[k] = v;
    }
    __syncthreads();
    if (k == 0) {
        float sum = 0.f;
        for (int i = 0; i < NUM_CLASSES; i++) sum += vals[i];
        out_reg[0] = 0.001f * sum / (float)NUM_CLASSES;
    }
}

// ---------------------------------------------------------------------------
extern "C" void kernel_launch(void* const* d_in, const int* in_sizes, int n_in,
                              void* d_out, int out_size, void* d_ws, size_t ws_size,
                              hipStream_t stream)
{
    const float* features  = (const float*)d_in[0];
    const float* objectness= (const float*)d_in[1];
    const float* rois_norm = (const float*)d_in[2];
    const int*   labels    = (const int*)  d_in[3];
    const float* W6  = (const float*)d_in[4];
    const float* b6  = (const float*)d_in[5];
    const float* W7  = (const float*)d_in[6];
    const float* b7  = (const float*)d_in[7];
    const float* W75 = (const float*)d_in[8];
    const float* b75 = (const float*)d_in[9];
    const float* Wc  = (const float*)d_in[10];
    const float* bc  = (const float*)d_in[11];
    const float* Wd  = (const float*)d_in[12];
    const float* bd  = (const float*)d_in[13];

    float* out = (float*)d_out;
    // d_out layout: [0:20] sums | [20:5140] scores | [5140:6164] rois | [6164] reg
    float* out_sums   = out;
    float* out_scores = out + 20;
    float* out_rois   = out + 20 + N_ROIS * NUM_CLASSES;
    float* out_reg    = out + 20 + N_ROIS * NUM_CLASSES + N_ROIS * 4;

    char* ws = (char*)d_ws;
    size_t off = 0;
    float* x   = (float*)(ws + off); off += (size_t)N_ROIS * D_IN * 4;   // 25.7 MB
    float* h1  = (float*)(ws + off); off += (size_t)N_ROIS * D6 * 4;     // 9.4 MB
    float* h2  = (float*)(ws + off); off += (size_t)N_ROIS * D7 * 4;     // 4.2 MB
    float* fc  = (float*)(ws + off); off += (size_t)N_ROIS * D75 * 4;    // 2.1 MB
    int*   rois_int   = (int*)(ws + off); off += N_ROIS * 4 * 4;
    float* cls_logits = (float*)(ws + off); off += N_ROIS * NUM_CLASSES * 4;
    float* det_logits = (float*)(ws + off); off += N_ROIS * NUM_CLASSES * 4;
    float* scores_ws  = (float*)(ws + off); off += N_ROIS * NUM_CLASSES * 4;
    int*   top_idx    = (int*)(ws + off); off += 256;
    float* norms      = (float*)(ws + off); off += N_ROIS * 4;
    float* dots       = (float*)(ws + off); off += N_ROIS * NUM_CLASSES * 4;

    topk_kernel<<<(NOBJ + 255) / 256, 256, 0, stream>>>(objectness, rois_norm,
                                                        rois_int, out_rois);
    crop_kernel<<<N_ROIS, 256, 0, stream>>>(features, rois_int, x);

    gemm_bias_relu<<<dim3(D6 / TN, N_ROIS / TM), 256, 0, stream>>>(
        x, W6, b6, h1, N_ROIS, D6, D_IN, 1);
    gemm_bias_relu<<<dim3(D7 / TN, N_ROIS / TM), 256, 0, stream>>>(
        h1, W7, b7, h2, N_ROIS, D7, D6, 1);
    gemm_bias_relu<<<dim3(D75 / TN, N_ROIS / TM), 256, 0, stream>>>(
        h2, W75, b75, fc, N_ROIS, D75, D7, 1);

    logits_kernel<<<N_ROIS, 256, 0, stream>>>(fc, Wc, bc, Wd, bd,
                                              cls_logits, det_logits);
    scores_kernel<<<1, 256, 0, stream>>>(cls_logits, det_logits, scores_ws,
                                         out_scores, out_sums, top_idx);
    norms_kernel<<<N_ROIS, 256, 0, stream>>>(fc, norms);
    dots_kernel<<<dim3(N_ROIS, NUM_CLASSES), 64, 0, stream>>>(fc, top_idx, dots);
    reg_kernel<<<1, 64, 0, stream>>>(labels, rois_int, top_idx, norms, dots,
                                     scores_ws, out_reg);
}

// Round 2
// 2128.435 us; speedup vs baseline: 2.2163x; 2.2163x over previous
//
#include <hip/hip_runtime.h>
#include <hip/hip_bf16.h>

// Problem constants
#define NUM_CLASSES 20
#define N_ROIS 256
#define POOL 7
#define HH 12
#define WW 12
#define CC 512
#define AA 9
#define NOBJ (HH*WW*AA)        // 1296
#define D_IN (POOL*POOL*CC)    // 25088
#define D6 9216
#define D7 4096
#define D75 2048

typedef __attribute__((ext_vector_type(8))) short bf16x8;
typedef __attribute__((ext_vector_type(4))) float f32x4;

// round-to-nearest-even f32 -> bf16 (bit pattern)
__device__ __forceinline__ unsigned short f2bf(float v) {
    unsigned int x = __float_as_uint(v);
    unsigned int r = (x + 0x7fffu + ((x >> 16) & 1u)) >> 16;
    return (unsigned short)r;
}
__device__ __forceinline__ float bf2f(unsigned short u) {
    unsigned int x = ((unsigned int)u) << 16;
    return __uint_as_float(x);
}

// ---------------------------------------------------------------------------
// Kernel 1: top-k select (stable descending) + box int'ization
// ---------------------------------------------------------------------------
__global__ __launch_bounds__(256) void topk_kernel(
    const float* __restrict__ obj, const float* __restrict__ rois_norm,
    int* __restrict__ rois_int, float* __restrict__ out_rois)
{
    __shared__ float so[NOBJ];
    for (int i = threadIdx.x; i < NOBJ; i += 256) so[i] = obj[i];
    __syncthreads();
    int i = blockIdx.x * 256 + threadIdx.x;
    if (i >= NOBJ) return;
    float v = so[i];
    int rank = 0;
    for (int j = 0; j < NOBJ; j++) {
        float u = so[j];
        rank += (u > v) || (u == v && j < i);
    }
    if (rank < N_ROIS) {
        float s0 = rois_norm[i*4+0], s1 = rois_norm[i*4+1];
        float s2 = rois_norm[i*4+2], s3 = rois_norm[i*4+3];
        float x1f = __fmul_rn(s0, 12.0f);
        float x2f = __fmul_rn(s1, 12.0f);
        float y1f = __fmul_rn(s2, 12.0f);
        float y2f = __fmul_rn(s3, 12.0f);
        int x1i = min(max((int)x1f, 0), HH - 1);
        int y1i = min(max((int)y1f, 0), WW - 1);
        int x2i = max(min(max((int)x2f, 0), HH), x1i + 1);
        int y2i = max(min(max((int)y2f, 0), WW), y1i + 1);
        rois_int[rank*4+0] = x1i; rois_int[rank*4+1] = x2i;
        rois_int[rank*4+2] = y1i; rois_int[rank*4+3] = y2i;
        out_rois[rank*4+0] = (float)x1i; out_rois[rank*4+1] = (float)x2i;
        out_rois[rank*4+2] = (float)y1i; out_rois[rank*4+3] = (float)y2i;
    }
}

// ---------------------------------------------------------------------------
// Kernel 2: crop + bilinear resize -> x_hi/x_lo bf16 split (N_ROIS, 7*7*512)
// ---------------------------------------------------------------------------
__global__ __launch_bounds__(256) void crop_kernel(
    const float* __restrict__ feats, const int* __restrict__ rois,
    unsigned short* __restrict__ x_hi, unsigned short* __restrict__ x_lo)
{
    int r = blockIdx.x;
    __shared__ int y0s[POOL], y1s[POOL], x0s[POOL], x1s[POOL];
    __shared__ float wys[POOL], wxs[POOL];
    if (threadIdx.x == 0) {
        int bx1 = rois[r*4+0], bx2 = rois[r*4+1];
        int by1 = rois[r*4+2], by2 = rois[r*4+3];
        float hf = (float)(by2 - by1), wf = (float)(bx2 - bx1);
        float y1f = (float)by1, y2m1 = (float)(by2 - 1);
        float x1f = (float)bx1, x2m1 = (float)(bx2 - 1);
        for (int i = 0; i < POOL; i++) {
            float g = __fdiv_rn(__fadd_rn((float)i, 0.5f), 7.0f);
            float ys = __fadd_rn(__fadd_rn(y1f, __fmul_rn(g, hf)), -0.5f);
            ys = fminf(fmaxf(ys, y1f), y2m1);
            float xs = __fadd_rn(__fadd_rn(x1f, __fmul_rn(g, wf)), -0.5f);
            xs = fminf(fmaxf(xs, x1f), x2m1);
            int y0 = (int)floorf(ys);
            int x0 = (int)floorf(xs);
            y0s[i] = y0; x0s[i] = x0;
            y1s[i] = min(y0 + 1, WW - 1);
            x1s[i] = min(x0 + 1, HH - 1);
            wys[i] = __fadd_rn(ys, -(float)y0);
            wxs[i] = __fadd_rn(xs, -(float)x0);
        }
    }
    __syncthreads();
    for (int idx = threadIdx.x; idx < D_IN; idx += 256) {
        int c = idx & (CC - 1);
        int ij = idx >> 9;
        int j = ij % POOL, i = ij / POOL;
        float wy = wys[i], wx = wxs[j];
        int y0 = y0s[i], y1n = y1s[i], x0 = x0s[j], x1n = x1s[j];
        float f00 = feats[(y0 * WW + x0 ) * CC + c];
        float f01 = feats[(y0 * WW + x1n) * CC + c];
        float f10 = feats[(y1n* WW + x0 ) * CC + c];
        float f11 = feats[(y1n* WW + x1n) * CC + c];
        float v = f00 * (1.f - wy) * (1.f - wx)
                + f01 * (1.f - wy) * wx
                + f10 * wy * (1.f - wx)
                + f11 * wy * wx;
        unsigned short h = f2bf(v);
        unsigned short l = f2bf(v - bf2f(h));
        size_t o = (size_t)r * D_IN + idx;
        x_hi[o] = h; x_lo[o] = l;
    }
}

// ---------------------------------------------------------------------------
// Kernel 3: split-precision bf16 MFMA GEMM (3 passes: AhBh + AhBl + AlBh)
// A (256 x K) as bf16 hi/lo, B (K x N_full) f32 streamed reg-direct,
// partial[kc][256][N_slice] f32 output (no bias/relu here).
// Block: 512 threads = 8 waves (4m x 2n), tile BM=256 BN=128 BK=32.
// ---------------------------------------------------------------------------
#define LDA 40   // ushort stride per A row in LDS: 80 B, 16B-aligned, <=2-way conflicts

__global__ __launch_bounds__(512, 2) void gemm_split(
    const unsigned short* __restrict__ A_hi,
    const unsigned short* __restrict__ A_lo,
    const float* __restrict__ B,
    float* __restrict__ partial,
    int N_full, int n_base, int N_slice, int K_total, int K_chunk)
{
    __shared__ unsigned short As_hi[256][LDA];   // 20.5 KB
    __shared__ unsigned short As_lo[256][LDA];   // 20.5 KB

    const int tid  = threadIdx.x;
    const int lane = tid & 63;
    const int wave = tid >> 6;
    const int wm   = wave & 3;    // m-wave 0..3 (64 rows each)
    const int wn   = wave >> 2;   // n-wave 0..1 (64 cols each)
    const int l15  = lane & 15;
    const int q    = lane >> 4;   // 0..3

    const int nblk   = blockIdx.x;
    const int kc     = blockIdx.y;
    const int kstart = kc * K_chunk;
    const int nsteps = K_chunk >> 5;

    // A staging assignment: thread -> (row, k-half)
    const int sm = tid >> 1;
    const int sk = (tid & 1) << 4;

    f32x4 acc[4][4];
#pragma unroll
    for (int i = 0; i < 4; i++)
#pragma unroll
        for (int j = 0; j < 4; j++)
            acc[i][j] = (f32x4){0.f, 0.f, 0.f, 0.f};

    const int n_gbase = n_base + nblk * 128 + wn * 64 + l15;

    for (int step = 0; step < nsteps; ++step) {
        const int k0 = kstart + (step << 5);

        // --- B loads direct-to-register in MFMA B-frag layout (issued early,
        // latency overlaps the A staging + barriers below)
        float bv[4][8];
        {
            const float* Bp = B + (size_t)(k0 + q * 8) * N_full + n_gbase;
#pragma unroll
            for (int j = 0; j < 4; j++) {
                const float* Bpj = Bp + j * 16;
#pragma unroll
                for (int jj = 0; jj < 8; jj++)
                    bv[j][jj] = Bpj[(size_t)jj * N_full];
            }
        }

        __syncthreads();   // previous step's frag reads complete
        {
            const uint4* gh = (const uint4*)(A_hi + (size_t)sm * K_total + k0 + sk);
            const uint4* gl = (const uint4*)(A_lo + (size_t)sm * K_total + k0 + sk);
            uint4 h0 = gh[0], h1 = gh[1];
            uint4 l0 = gl[0], l1 = gl[1];
            *(uint4*)&As_hi[sm][sk]     = h0;
            *(uint4*)&As_hi[sm][sk + 8] = h1;
            *(uint4*)&As_lo[sm][sk]     = l0;
            *(uint4*)&As_lo[sm][sk + 8] = l1;
        }
        __syncthreads();

        // A fragments from LDS
        bf16x8 Ah[4], Al[4];
#pragma unroll
        for (int i = 0; i < 4; i++) {
            int am = wm * 64 + i * 16 + l15;
            Ah[i] = *(const bf16x8*)&As_hi[am][q * 8];
            Al[i] = *(const bf16x8*)&As_lo[am][q * 8];
        }

#pragma unroll
        for (int j = 0; j < 4; j++) {
            bf16x8 bh, bl;
#pragma unroll
            for (int jj = 0; jj < 8; jj++) {
                float v = bv[j][jj];
                unsigned short h = f2bf(v);
                unsigned short lo = f2bf(v - bf2f(h));
                bh[jj] = (short)h;
                bl[jj] = (short)lo;
            }
#pragma unroll
            for (int i = 0; i < 4; i++) {
                acc[i][j] = __builtin_amdgcn_mfma_f32_16x16x32_bf16(Ah[i], bh, acc[i][j], 0, 0, 0);
                acc[i][j] = __builtin_amdgcn_mfma_f32_16x16x32_bf16(Ah[i], bl, acc[i][j], 0, 0, 0);
                acc[i][j] = __builtin_amdgcn_mfma_f32_16x16x32_bf16(Al[i], bh, acc[i][j], 0, 0, 0);
            }
        }
    }

    // epilogue: raw partial store (C/D layout: col=lane&15, row=q*4+reg)
    float* P = partial + (size_t)kc * 256 * N_slice;
#pragma unroll
    for (int i = 0; i < 4; i++) {
        int mrow = wm * 64 + i * 16 + q * 4;
#pragma unroll
        for (int j = 0; j < 4; j++) {
            int ln = nblk * 128 + wn * 64 + j * 16 + l15;
#pragma unroll
            for (int r = 0; r < 4; r++)
                P[(size_t)(mrow + r) * N_slice + ln] = acc[i][j][r];
        }
    }
}

// ---------------------------------------------------------------------------
// Kernel 4: reduce k-split partials + bias + relu, emit bf16 hi/lo (+opt f32)
// ---------------------------------------------------------------------------
__global__ __launch_bounds__(256) void reduce_bias_relu_split(
    const float* __restrict__ partial, const float* __restrict__ bias,
    float* __restrict__ C_f32,
    unsigned short* __restrict__ C_hi, unsigned short* __restrict__ C_lo,
    int N_slice, int N_full, int n_base, int ksplit)
{
    int idx = blockIdx.x * 256 + threadIdx.x;   // < 256*N_slice
    int m = idx / N_slice;
    int ln = idx - m * N_slice;
    float s = 0.f;
    for (int kc = 0; kc < ksplit; ++kc)
        s += partial[(size_t)kc * 256 * N_slice + idx];
    s += bias[n_base + ln];
    s = fmaxf(s, 0.f);
    size_t o = (size_t)m * N_full + n_base + ln;
    unsigned short h = f2bf(s);
    unsigned short lo = f2bf(s - bf2f(h));
    C_hi[o] = h; C_lo[o] = lo;
    if (C_f32) C_f32[o] = s;
}

// ---------------------------------------------------------------------------
// Kernel 5: classification/detection logits (per-ROI block)
// ---------------------------------------------------------------------------
__global__ __launch_bounds__(256) void logits_kernel(
    const float* __restrict__ fc,
    const float* __restrict__ Wc, const float* __restrict__ bc,
    const float* __restrict__ Wd, const float* __restrict__ bd,
    float* __restrict__ cls_logits, float* __restrict__ det_logits)
{
    int r = blockIdx.x;
    __shared__ float row[D75];
    for (int d = threadIdx.x; d < D75; d += 256) row[d] = fc[(size_t)r * D75 + d];
    __syncthreads();
    int t = threadIdx.x;
    if (t < NUM_CLASSES) {
        float s = 0.f;
        for (int d = 0; d < D75; d++) s += row[d] * Wc[d * NUM_CLASSES + t];
        cls_logits[r * NUM_CLASSES + t] = s + bc[t];
    } else if (t >= 64 && t < 64 + NUM_CLASSES) {
        int k = t - 64;
        float s = 0.f;
        for (int d = 0; d < D75; d++) s += row[d] * Wd[d * NUM_CLASSES + k];
        det_logits[r * NUM_CLASSES + k] = s + bd[k];
    }
}

// ---------------------------------------------------------------------------
// Kernel 6: softmaxes, scores, column sums (output 0), argmin per class
// ---------------------------------------------------------------------------
__global__ __launch_bounds__(256) void scores_kernel(
    const float* __restrict__ cls_logits, const float* __restrict__ det_logits,
    float* __restrict__ scores_ws, float* __restrict__ out_scores,
    float* __restrict__ out_sums, int* __restrict__ top_idx)
{
    __shared__ float cl[N_ROIS][NUM_CLASSES];
    __shared__ float dv[N_ROIS][NUM_CLASSES];
    __shared__ float cmax[NUM_CLASSES], csum[NUM_CLASSES];
    int r = threadIdx.x;
    float dl[NUM_CLASSES];
    float m = -1e30f;
    for (int k = 0; k < NUM_CLASSES; k++) {
        dl[k] = det_logits[r * NUM_CLASSES + k];
        m = fmaxf(m, dl[k]);
    }
    float s = 0.f;
    for (int k = 0; k < NUM_CLASSES; k++) { dl[k] = expf(dl[k] - m); s += dl[k]; }
    for (int k = 0; k < NUM_CLASSES; k++) dv[r][k] = dl[k] / s;
    for (int k = 0; k < NUM_CLASSES; k++) cl[r][k] = cls_logits[r * NUM_CLASSES + k];
    __syncthreads();
    if (r < NUM_CLASSES) {
        float mm = -1e30f;
        for (int i = 0; i < N_ROIS; i++) mm = fmaxf(mm, cl[i][r]);
        float ss = 0.f;
        for (int i = 0; i < N_ROIS; i++) ss += expf(cl[i][r] - mm);
        cmax[r] = mm; csum[r] = ss;
    }
    __syncthreads();
    float sc[NUM_CLASSES];
    for (int k = 0; k < NUM_CLASSES; k++) {
        sc[k] = (expf(cl[r][k] - cmax[k]) / csum[k]) * dv[r][k];
        scores_ws[r * NUM_CLASSES + k] = sc[k];
        out_scores[r * NUM_CLASSES + k] = sc[k];
    }
    __syncthreads();
    for (int k = 0; k < NUM_CLASSES; k++) cl[r][k] = sc[k];
    __syncthreads();
    if (r < NUM_CLASSES) {
        float sum = 0.f, mn = 1e30f;
        int mi = 0;
        for (int i = 0; i < N_ROIS; i++) {
            float v = cl[i][r];
            sum += v;
            if (v < mn) { mn = v; mi = i; }
        }
        out_sums[r] = fminf(fmaxf(sum, 0.f), 1.f);
        top_idx[r] = mi;
    }
}

// ---------------------------------------------------------------------------
// Kernel 7: per-row squared norms of fc
// ---------------------------------------------------------------------------
__global__ __launch_bounds__(256) void norms_kernel(
    const float* __restrict__ fc, float* __restrict__ norms)
{
    int r = blockIdx.x;
    float s = 0.f;
    for (int d = threadIdx.x; d < D75; d += 256) {
        float v = fc[(size_t)r * D75 + d];
        s += v * v;
    }
    __shared__ float red[256];
    red[threadIdx.x] = s;
    __syncthreads();
    for (int off = 128; off > 0; off >>= 1) {
        if (threadIdx.x < off) red[threadIdx.x] += red[threadIdx.x + off];
        __syncthreads();
    }
    if (threadIdx.x == 0) norms[r] = red[0];
}

// ---------------------------------------------------------------------------
// Kernel 8: dots[r][k] = fc[r] . fc[top_idx[k]]
// ---------------------------------------------------------------------------
__global__ __launch_bounds__(64) void dots_kernel(
    const float* __restrict__ fc, const int* __restrict__ top_idx,
    float* __restrict__ dots)
{
    int r = blockIdx.x, k = blockIdx.y;
    int t = top_idx[k];
    const float* a = fc + (size_t)r * D75;
    const float* b = fc + (size_t)t * D75;
    float s = 0.f;
    for (int d = threadIdx.x; d < D75; d += 64) s += a[d] * b[d];
    for (int off = 32; off > 0; off >>= 1) s += __shfl_down(s, off);
    if (threadIdx.x == 0) dots[r * NUM_CLASSES + k] = s;
}

// ---------------------------------------------------------------------------
// Kernel 9: spatial regularization scalar
// ---------------------------------------------------------------------------
__global__ __launch_bounds__(64) void reg_kernel(
    const int* __restrict__ labels, const int* __restrict__ rois,
    const int* __restrict__ top_idx, const float* __restrict__ norms,
    const float* __restrict__ dots, const float* __restrict__ scores,
    float* __restrict__ out_reg)
{
    __shared__ float vals[NUM_CLASSES];
    int k = threadIdx.x;
    if (k < NUM_CLASSES) {
        float v = 0.f;
        if (labels[k] > 0) {
            int t = top_idx[k];
            float T = norms[t];
            float rx1 = (float)rois[t*4+0], rx2 = (float)rois[t*4+1];
            float ry1 = (float)rois[t*4+2], ry2 = (float)rois[t*4+3];
            float aref = fmaxf(rx2 - rx1 + 1.f, 0.f) * fmaxf(ry2 - ry1 + 1.f, 0.f);
            float acc = 0.f;
            for (int r = 0; r < N_ROIS; r++) {
                if (r == t) continue;
                float bx1 = (float)rois[r*4+0], bx2 = (float)rois[r*4+1];
                float by1 = (float)rois[r*4+2], by2 = (float)rois[r*4+3];
                float ix1 = fmaxf(bx1, rx1), iy1 = fmaxf(by1, ry1);
                float ix2 = fminf(bx2, rx2), iy2 = fminf(by2, ry2);
                float inter = fmaxf(ix2 - ix1 + 1.f, 0.f) * fmaxf(iy2 - iy1 + 1.f, 0.f);
                float a1 = fmaxf(bx2 - bx1 + 1.f, 0.f) * fmaxf(by2 - by1 + 1.f, 0.f);
                float iou = inter / (a1 + aref - inter);
                float s = scores[r * NUM_CLASSES + k];
                float term = (iou > 0.5f)
                           ? (norms[r] - 2.f * dots[r * NUM_CLASSES + k] + T)
                           : T;
                acc += s * s * term;
            }
            v = 0.5f * acc;
        }
        vals[k] = v;
    }
    __syncthreads();
    if (k == 0) {
        float sum = 0.f;
        for (int i = 0; i < NUM_CLASSES; i++) sum += vals[i];
        out_reg[0] = 0.001f * sum / (float)NUM_CLASSES;
    }
}

// ---------------------------------------------------------------------------
extern "C" void kernel_launch(void* const* d_in, const int* in_sizes, int n_in,
                              void* d_out, int out_size, void* d_ws, size_t ws_size,
                              hipStream_t stream)
{
    const float* features  = (const float*)d_in[0];
    const float* objectness= (const float*)d_in[1];
    const float* rois_norm = (const float*)d_in[2];
    const int*   labels    = (const int*)  d_in[3];
    const float* W6  = (const float*)d_in[4];
    const float* b6  = (const float*)d_in[5];
    const float* W7  = (const float*)d_in[6];
    const float* b7  = (const float*)d_in[7];
    const float* W75 = (const float*)d_in[8];
    const float* b75 = (const float*)d_in[9];
    const float* Wc  = (const float*)d_in[10];
    const float* bc  = (const float*)d_in[11];
    const float* Wd  = (const float*)d_in[12];
    const float* bd  = (const float*)d_in[13];

    float* out = (float*)d_out;
    float* out_sums   = out;
    float* out_scores = out + 20;
    float* out_rois   = out + 20 + N_ROIS * NUM_CLASSES;
    float* out_reg    = out + 20 + N_ROIS * NUM_CLASSES + N_ROIS * 4;

    char* ws = (char*)d_ws;
    size_t off = 0;
    auto alloc = [&](size_t bytes) { void* p = ws + off; off += (bytes + 255) & ~(size_t)255; return p; };

    unsigned short* x_hi  = (unsigned short*)alloc((size_t)N_ROIS * D_IN * 2);
    unsigned short* x_lo  = (unsigned short*)alloc((size_t)N_ROIS * D_IN * 2);
    unsigned short* h1_hi = (unsigned short*)alloc((size_t)N_ROIS * D6 * 2);
    unsigned short* h1_lo = (unsigned short*)alloc((size_t)N_ROIS * D6 * 2);
    unsigned short* h2_hi = (unsigned short*)alloc((size_t)N_ROIS * D7 * 2);
    unsigned short* h2_lo = (unsigned short*)alloc((size_t)N_ROIS * D7 * 2);
    float* fc_f32         = (float*)alloc((size_t)N_ROIS * D75 * 4);
    unsigned short* fc_hi = (unsigned short*)alloc((size_t)N_ROIS * D75 * 2);
    unsigned short* fc_lo = (unsigned short*)alloc((size_t)N_ROIS * D75 * 2);
    float* partial        = (float*)alloc((size_t)16 * 256 * 2048 * 4); // 33.5 MB, reused per layer
    int*   rois_int   = (int*)alloc(N_ROIS * 4 * 4);
    float* cls_logits = (float*)alloc(N_ROIS * NUM_CLASSES * 4);
    float* det_logits = (float*)alloc(N_ROIS * NUM_CLASSES * 4);
    float* scores_ws  = (float*)alloc(N_ROIS * NUM_CLASSES * 4);
    int*   top_idx    = (int*)alloc(256);
    float* norms      = (float*)alloc(N_ROIS * 4);
    float* dots       = (float*)alloc(N_ROIS * NUM_CLASSES * 4);
    // total ws usage ~78 MB

    topk_kernel<<<(NOBJ + 255) / 256, 256, 0, stream>>>(objectness, rois_norm,
                                                        rois_int, out_rois);
    crop_kernel<<<N_ROIS, 256, 0, stream>>>(features, rois_int, x_hi, x_lo);

    // FC6 in two N-halves (keeps partial buffer <=34MB, 252 blocks/launch)
    for (int half = 0; half < 2; half++) {
        gemm_split<<<dim3(36, 7), 512, 0, stream>>>(
            x_hi, x_lo, W6, partial, D6, half * 4608, 4608, D_IN, 3584);
        reduce_bias_relu_split<<<4608, 256, 0, stream>>>(
            partial, b6, nullptr, h1_hi, h1_lo, 4608, D6, half * 4608, 7);
    }
    // FC7: grid 32x8 = 256 blocks
    gemm_split<<<dim3(32, 8), 512, 0, stream>>>(
        h1_hi, h1_lo, W7, partial, D7, 0, D7, D6, 1152);
    reduce_bias_relu_split<<<4096, 256, 0, stream>>>(
        partial, b7, nullptr, h2_hi, h2_lo, D7, D7, 0, 8);
    // FC75: grid 16x16 = 256 blocks
    gemm_split<<<dim3(16, 16), 512, 0, stream>>>(
        h2_hi, h2_lo, W75, partial, D75, 0, D75, D7, 256);
    reduce_bias_relu_split<<<2048, 256, 0, stream>>>(
        partial, b75, fc_f32, fc_hi, fc_lo, D75, D75, 0, 16);

    logits_kernel<<<N_ROIS, 256, 0, stream>>>(fc_f32, Wc, bc, Wd, bd,
                                              cls_logits, det_logits);
    scores_kernel<<<1, 256, 0, stream>>>(cls_logits, det_logits, scores_ws,
                                         out_scores, out_sums, top_idx);
    norms_kernel<<<N_ROIS, 256, 0, stream>>>(fc_f32, norms);
    dots_kernel<<<dim3(N_ROIS, NUM_CLASSES), 64, 0, stream>>>(fc_f32, top_idx, dots);
    reg_kernel<<<1, 64, 0, stream>>>(labels, rois_int, top_idx, norms, dots,
                                     scores_ws, out_reg);
}